// Round 8
// baseline (1508.438 us; speedup 1.0000x reference)
//
#include <hip/hip_runtime.h>

typedef unsigned short u16;
typedef short s16x8 __attribute__((ext_vector_type(8)));
typedef u16 u16x8 __attribute__((ext_vector_type(8)));
typedef u16 u16x4 __attribute__((ext_vector_type(4)));
typedef float f32x4 __attribute__((ext_vector_type(4)));

#define DEV __device__ __forceinline__

DEV float bf2f(u16 x) { unsigned v = ((unsigned)x) << 16; float f; __builtin_memcpy(&f, &v, 4); return f; }
DEV u16 f2bf(float f) { unsigned u; __builtin_memcpy(&u, &f, 4); u += 0x7FFFu + ((u >> 16) & 1u); return (u16)(u >> 16); }

// async global->LDS DMA, 16B per lane. LDS dest = wave-uniform base + lane*16.
DEV void gload16(const u16* g, u16* l) {
  __builtin_amdgcn_global_load_lds((const __attribute__((address_space(1))) void*)g,
                                   (__attribute__((address_space(3))) void*)l, 16, 0, 0);
}

// ---------------- dtype detector: bf16 data as bf16 maxes ~5; f32 data as bf16 explodes ----------------
__global__ void detect_dtype(const u16* __restrict__ x, int* __restrict__ flag) {
  int tid = threadIdx.x;
  float mx = 0.f;
  for (int i = tid; i < 4096; i += 256) mx = fmaxf(mx, fabsf(bf2f(x[i])));
  __shared__ float red[4];
  int wave = tid >> 6, lane = tid & 63;
  for (int off = 32; off; off >>= 1) mx = fmaxf(mx, __shfl_xor(mx, off));
  if (lane == 0) red[wave] = mx;
  __syncthreads();
  if (tid == 0) {
    mx = fmaxf(fmaxf(red[0], red[1]), fmaxf(red[2], red[3]));
    *flag = (mx > 1e4f) ? 1 : 0;   // 1 = inputs are float32
  }
}

// ---------------- batched small-input canonicalizer: 28 tensors in ONE dispatch ----------------
struct CvBatch {
  const void* src[28];
  unsigned dstOff[28];     // u16 units from dstBase
  unsigned n[28];          // element count
  unsigned chunkStart[29]; // prefix of ceil(n/2048)
  int cnt;
};

__global__ __launch_bounds__(256) void convert_batch(CvBatch cb, u16* __restrict__ dstBase,
                                                     const int* __restrict__ flag) {
  const int isF = *flag;
  const unsigned bid = blockIdx.x;
  int j = 0;
  while (bid >= cb.chunkStart[j + 1]) ++j;
  const unsigned base = (bid - cb.chunkStart[j]) * 2048 + threadIdx.x * 8;
  const unsigned n = cb.n[j];
  if (base >= n) return;
  u16* dst = dstBase + cb.dstOff[j];
  const void* src = cb.src[j];
  if (base + 8 <= n) {
    u16x8 v;
    if (isF) {
      const float* f = (const float*)src;
#pragma unroll
      for (int k = 0; k < 8; ++k) v[k] = f2bf(f[base + k]);
    } else {
      v = *(const u16x8*)&((const u16*)src)[base];
    }
    *(u16x8*)&dst[base] = v;
  } else {
    for (unsigned i = base; i < n; ++i)
      dst[i] = isF ? f2bf(((const float*)src)[i]) : ((const u16*)src)[i];
  }
}

// ---------------- BN prep: scale = g*rsqrt(v+eps), shift = b - m*scale ----------------
__global__ void bn_prep(const u16* __restrict__ cbn, float* __restrict__ out) {
  int w = blockIdx.x;
  const u16* bn = cbn + w * 2048;
  int c = threadIdx.x;
  float g = bf2f(bn[c]), be = bf2f(bn[512 + c]), m = bf2f(bn[1024 + c]), v = bf2f(bn[1536 + c]);
  float sc = g * rsqrtf(v + 1e-5f);
  out[w * 1024 + c] = sc;
  out[w * 1024 + 512 + c] = be - m * sc;
}

// ---------------- weight repack (O,I,3,3) -> (O,3,3,I), 3 weight sets per dispatch (grid.z) ----------------
struct Repack3P { const void* src[3]; u16* dst[3]; };

__global__ __launch_bounds__(256) void repack_w3(Repack3P rp, int I, int Ishift,
                                                 const int* __restrict__ flag) {
  const int isF = *flag;
  const void* w = rp.src[blockIdx.z];
  u16* wr = rp.dst[blockIdx.z];
  size_t idx = ((size_t)blockIdx.x * 256 + threadIdx.x) * 8;
  int i0 = (int)(idx & (size_t)(I - 1));
  int t = (int)(idx >> Ishift);
  int o = t / 9, kk = t - o * 9;
  u16x8 v;
  if (isF) {
    const float* f = (const float*)w;
#pragma unroll
    for (int j = 0; j < 8; ++j) v[j] = f2bf(f[((size_t)o * I + i0 + j) * 9 + kk]);
  } else {
    const u16* bsrc = (const u16*)w;
#pragma unroll
    for (int j = 0; j < 8; ++j) v[j] = bsrc[((size_t)o * I + i0 + j) * 9 + kk];
  }
  *(u16x8*)&wr[idx] = v;
}

// ---------------- border-only zeroing of a padded (B,66,66,CIN) NHWC buffer ----------------
__global__ __launch_bounds__(256) void zero_border(u16* __restrict__ base, int CIN) {
  int p = blockIdx.x, b = blockIdx.y;
  int py, px;
  if (p < 66)       { py = 0;        px = p; }
  else if (p < 132) { py = 65;       px = p - 66; }
  else if (p < 196) { py = p - 131;  px = 0; }    // py 1..64
  else              { py = p - 195;  px = 65; }   // py 1..64
  u16* d = base + (((size_t)b * 66 + py) * 66 + px) * (size_t)CIN;
  for (int i = threadIdx.x * 8; i < CIN; i += 2048) {
    u16x8 z;
#pragma unroll
    for (int k = 0; k < 8; ++k) z[k] = 0;
    *(u16x8*)&d[i] = z;
  }
}

// ---------------- x NCHW -> padded NHWC (B,66,66,2048), borders pre-zeroed; raw input ----------------
__global__ __launch_bounds__(256) void pad_nchw(const void* __restrict__ x, u16* __restrict__ xpad,
                                                const int* __restrict__ flag) {
  __shared__ u16 t[64][72];
  const int isF = *flag;
  int c0 = blockIdx.x * 64, h = blockIdx.y, b = blockIdx.z;
  int tid = threadIdx.x;
#pragma unroll
  for (int i = 0; i < 2; ++i) {
    int idx = i * 256 + tid;
    int cc = idx >> 3, ww = (idx & 7) * 8;
    size_t base = (((size_t)(b * 2048 + c0 + cc) * 64) + h) * 64 + ww;
    u16x8 v;
    if (isF) {
      const float* fx = (const float*)x;
#pragma unroll
      for (int j = 0; j < 8; ++j) v[j] = f2bf(fx[base + j]);
    } else {
      v = *(const u16x8*)&((const u16*)x)[base];
    }
    *(u16x8*)&t[cc][ww] = v;
  }
  __syncthreads();
#pragma unroll
  for (int i = 0; i < 2; ++i) {
    int idx = i * 256 + tid;
    int ww = idx >> 3, cc = (idx & 7) * 8;
    u16x8 v;
#pragma unroll
    for (int j = 0; j < 8; ++j) v[j] = t[cc + j][ww];
    *(u16x8*)&xpad[(((size_t)b * 66 + h + 1) * 66 + ww + 1) * 2048 + c0 + cc] = v;
  }
}

// ---------------- generic bf16 transpose (R,C)->(C,R) per batch ----------------
__global__ __launch_bounds__(256) void transpose64(const u16* __restrict__ src, u16* __restrict__ dst,
                                                   int R, int C) {
  __shared__ u16 t[64][72];
  int r0 = blockIdx.x * 64, c0 = blockIdx.y * 64;
  const u16* s = src + (size_t)blockIdx.z * R * C;
  u16* d = dst + (size_t)blockIdx.z * R * C;
  int tid = threadIdx.x;
#pragma unroll
  for (int i = 0; i < 2; ++i) {
    int idx = i * 256 + tid;
    int rr = idx >> 3, cc = (idx & 7) * 8;
    u16x8 v = *(const u16x8*)&s[(size_t)(r0 + rr) * C + c0 + cc];
    *(u16x8*)&t[rr][cc] = v;
  }
  __syncthreads();
#pragma unroll
  for (int i = 0; i < 2; ++i) {
    int idx = i * 256 + tid;
    int cc = idx >> 3, rr = (idx & 7) * 8;
    u16x8 v;
#pragma unroll
    for (int j = 0; j < 8; ++j) v[j] = t[rr + j][cc];
    *(u16x8*)&d[(size_t)(c0 + cc) * R + r0 + rr] = v;
  }
}

// ---------------- unified NT GEMM: C[m,n] = sum_k A[m,k]*B[n,k] ----------------
// R12: 2-phase double-buffer (T3 minimum): stage tile k+1 BEFORE computing tile k, so the
// barrier's vmcnt(0) drain is covered by ds_read+MFMA. BK=32, 2 buffers -> same LDS as R10.
// EPI: 0 = bf16 store (+bias, *rowscale; optional fused 2nd problem via B2/bias2/out2)
//      1 = bf16 transposed store ; 2 = fp32 store (LDS-bounced f32x4) ; 3 = alpha*acc+residual -> padded NHWC
// Requires K % 32 == 0.
struct GemmP {
  const u16* A; const u16* B;
  long aBatch, bBatch;
  int M, N, K;
  u16* out; long outBatch; int ldOut;
  const u16* bias;
  const u16* rowscale;
  const u16* residual; long resBatch; int ldRes;
  const u16* alphaPtr;
  float* outF; long outFBatch;
  const u16* B2; const u16* bias2; u16* out2;
};

template <int BM, int BN, int EPI>
__global__ __launch_bounds__(256) void gemm_nt(GemmP p) {
  static_assert(EPI != 2 || BM >= BN, "EPI2 LDS bounce needs BM>=BN");
  constexpr int HB = (BM + BN) * 32;   // u16 per buffer (A tile then B tile)
  __shared__ __align__(16) u16 ls[2][HB];
  const int tid = threadIdx.x;
  int bz = blockIdx.z;
  const u16* Bsel = p.B;
  const u16* biasSel = p.bias;
  u16* outSel = p.out;
  if (EPI == 0 && p.out2) {
    const int h = gridDim.z >> 1;
    if (bz >= h) { bz -= h; Bsel = p.B2; biasSel = p.bias2; outSel = p.out2; }
  }
  const int m0 = blockIdx.x * BM, n0 = blockIdx.y * BN;
  const u16* A = p.A + (size_t)bz * p.aBatch;
  const u16* Bp = Bsel + (size_t)bz * p.bBatch;
  const int wave = tid >> 6, lane = tid & 63;
  const int quad = lane >> 4, r16 = lane & 15;
  const int wm = (wave >> 1) * (BM / 2), wn = (wave & 1) * (BN / 2);
  constexpr int TM = BM / 32, TN = BN / 32;
  f32x4 acc[TM][TN] = {};
  const int srow = tid >> 2, sch = (tid & 3) * 8;
  const int K = p.K;
  auto stage = [&](int buf, int k0) {
#pragma unroll
    for (int i = 0; i < BM / 64; ++i)
      gload16(&A[(size_t)(m0 + i * 64 + srow) * K + k0 + sch], &ls[buf][i * 2048 + wave * 512]);
#pragma unroll
    for (int i = 0; i < BN / 64; ++i)
      gload16(&Bp[(size_t)(n0 + i * 64 + srow) * K + k0 + sch],
              &ls[buf][BM * 32 + i * 2048 + wave * 512]);
  };
  stage(0, 0);
  __syncthreads();  // vmcnt(0) drain: buffer 0 ready
  int cur = 0;
  for (int k0 = 0; k0 < K; k0 += 32) {
    if (k0 + 32 < K) stage(cur ^ 1, k0 + 32);   // issue next tile; drained at THIS iter's barrier
    const u16* lA = &ls[cur][0];
    const u16* lB = &ls[cur][BM * 32];
    s16x8 av[TM], bv[TN];
#pragma unroll
    for (int t = 0; t < TM; ++t) av[t] = *(const s16x8*)&lA[(wm + t * 16 + r16) * 32 + quad * 8];
#pragma unroll
    for (int t = 0; t < TN; ++t) bv[t] = *(const s16x8*)&lB[(wn + t * 16 + r16) * 32 + quad * 8];
#pragma unroll
    for (int i = 0; i < TM; ++i)
#pragma unroll
      for (int j = 0; j < TN; ++j)
        acc[i][j] = __builtin_amdgcn_mfma_f32_16x16x32_bf16(av[i], bv[j], acc[i][j], 0, 0, 0);
    __syncthreads();  // all reads of ls[cur] done + next-tile staging drained
    cur ^= 1;
  }
  if constexpr (EPI == 2) {
    // LDS-bounced vector stores: per i, this block's 32 rows x BN cols go through LDS fp32,
    // then read back row-major and stored f32x4 (256B segments vs 64B scalar).
    float* lsF = (float*)&ls[0][0];   // capacity (BM+BN)*128 B >= 32*BN*4 B
#pragma unroll
    for (int i = 0; i < TM; ++i) {
      __syncthreads();
#pragma unroll
      for (int j = 0; j < TN; ++j) {
        const int col = wn + j * 16 + r16;
#pragma unroll
        for (int r = 0; r < 4; ++r) {
          const int rowL = (wave >> 1) * 16 + quad * 4 + r;
          lsF[rowL * BN + col] = acc[i][j][r];
        }
      }
      __syncthreads();
      constexpr int PASSES = (32 * BN) / 1024;
#pragma unroll
      for (int pp = 0; pp < PASSES; ++pp) {
        const int lin = (pp * 256 + tid) * 4;
        const int rowL = lin / BN, col = lin & (BN - 1);
        const int gm = m0 + (rowL >> 4) * (BM / 2) + i * 16 + (rowL & 15);
        *(f32x4*)&p.outF[(size_t)bz * p.outFBatch + (size_t)gm * p.ldOut + (n0 + col)] =
            *(const f32x4*)&lsF[lin];
      }
    }
    return;
  }
  float alpha = 0.f;
  if (EPI == 3) alpha = bf2f(p.alphaPtr[0]);
#pragma unroll
  for (int i = 0; i < TM; ++i) {
#pragma unroll
    for (int j = 0; j < TN; ++j) {
      const int nn = n0 + wn + j * 16 + r16;
      float bia = 0.f;
      if ((EPI == 0 || EPI == 1) && biasSel) bia = bf2f(biasSel[nn]);
#pragma unroll
      for (int r = 0; r < 4; ++r) {
        const int mm = m0 + wm + i * 16 + quad * 4 + r;
        float v = acc[i][j][r];
        if (EPI == 0) {
          v += bia;
          if (p.rowscale) v *= bf2f(p.rowscale[mm]);
          outSel[(size_t)bz * p.outBatch + (size_t)mm * p.ldOut + nn] = f2bf(v);
        } else if (EPI == 1) {
          v += bia;
          if (p.rowscale) v *= bf2f(p.rowscale[mm]);
          p.out[(size_t)bz * p.outBatch + (size_t)nn * p.ldOut + mm] = f2bf(v);
        } else {
          float res = bf2f(p.residual[(size_t)bz * p.resBatch + (size_t)mm * p.ldRes + nn]);
          v = alpha * v + res;
          const int py = mm >> 6, px = mm & 63;
          p.out[(size_t)bz * p.outBatch + ((size_t)(py + 1) * 66 + (px + 1)) * p.ldOut + nn] = f2bf(v);
        }
      }
    }
  }
}

// ---------------- fused 3-conv 3x3 (implicit GEMM) + BN + ReLU, NHWC padded input ----------------
// blockIdx.z in [0,6): ci = z>>1 selects conv (input/weights/output), b = z&1 batch.
// R12: 2-phase double-buffer over flattened (c-chunk outer, 9-tap inner) iteration.
// BK=32 x 2 buffers = 32 KB LDS (same as R11); one barrier per 32-k, drain hidden under compute.
struct Conv3P {
  const u16* in[3];
  const u16* wr[3];
  u16* out[3];
  const float* bn;   // conv ci: scale = bn[ci*1024 + n], shift = bn[ci*1024 + 512 + n]
};

template <int CIN>
__global__ __launch_bounds__(256) void conv3x3_k(Conv3P p) {
  __shared__ __align__(16) u16 ls[2][8192];  // per buf: A rows0-63 | A rows64-127 | B rows0-63 | B rows64-127
  const int tid = threadIdx.x;
  const int z = blockIdx.z, ci = z >> 1, b = z & 1;
  const int m0 = blockIdx.x * 128, n0 = blockIdx.y * 128;
  const u16* __restrict__ xin = p.in[ci];
  const u16* __restrict__ wr = p.wr[ci];
  const int wave = tid >> 6, lane = tid & 63;
  const int quad = lane >> 4, r16 = lane & 15;
  const int wm = (wave >> 1) * 64, wn = (wave & 1) * 64;
  f32x4 acc[4][4] = {};
  const int srow = tid >> 2, sch = (tid & 3) * 8;
  const int p0 = m0 + srow, p1 = p0 + 64;
  const size_t a0 = (((size_t)b * 66 + (p0 >> 6)) * 66 + (p0 & 63)) * CIN + sch;
  const size_t a1 = (((size_t)b * 66 + (p1 >> 6)) * 66 + (p1 & 63)) * CIN + sch;
  const size_t b0 = ((size_t)(n0 + srow) * 9) * CIN + sch;
  const size_t b1 = ((size_t)(n0 + 64 + srow) * 9) * CIN + sch;
  auto stage = [&](int buf, int kh, int kw, int c) {
    const size_t soff = ((size_t)(kh * 66 + kw)) * CIN + c;
    const size_t woff = (size_t)(kh * 3 + kw) * CIN + c;
    u16* base = &ls[buf][0];
    gload16(&xin[a0 + soff], base + wave * 512);
    gload16(&xin[a1 + soff], base + 2048 + wave * 512);
    gload16(&wr[b0 + woff], base + 4096 + wave * 512);
    gload16(&wr[b1 + woff], base + 6144 + wave * 512);
  };
  const int NT = (CIN / 32) * 9;
  stage(0, 0, 0, 0);
  __syncthreads();  // vmcnt(0) drain: buffer 0 ready
  int cur = 0;
  int khN = 0, kwN = 1, cN = 0;  // indices of iteration t=1
  for (int t = 0; t < NT; ++t) {
    if (t + 1 < NT) {
      stage(cur ^ 1, khN, kwN, cN);   // issue next tile; drained at THIS iter's barrier
      if (++kwN == 3) { kwN = 0; if (++khN == 3) { khN = 0; cN += 32; } }
    }
    const u16* base = &ls[cur][0];
    s16x8 av[4], bv[4];
#pragma unroll
    for (int tt = 0; tt < 4; ++tt)
      av[tt] = *(const s16x8*)&base[(wm + tt * 16 + r16) * 32 + quad * 8];
#pragma unroll
    for (int tt = 0; tt < 4; ++tt)
      bv[tt] = *(const s16x8*)&base[4096 + (wn + tt * 16 + r16) * 32 + quad * 8];
#pragma unroll
    for (int i = 0; i < 4; ++i)
#pragma unroll
      for (int j = 0; j < 4; ++j)
        acc[i][j] = __builtin_amdgcn_mfma_f32_16x16x32_bf16(av[i], bv[j], acc[i][j], 0, 0, 0);
    __syncthreads();  // all reads of ls[cur] done + next-tile staging drained
    cur ^= 1;
  }
  u16* __restrict__ out = p.out[ci];
  const float* bnS = p.bn + ci * 1024;
#pragma unroll
  for (int i = 0; i < 4; ++i) {
#pragma unroll
    for (int j = 0; j < 4; ++j) {
      const int nn = n0 + wn + j * 16 + r16;
      const float s = bnS[nn], sh = bnS[512 + nn];
#pragma unroll
      for (int r = 0; r < 4; ++r) {
        const int mm = m0 + wm + i * 16 + quad * 4 + r;
        float v = fmaxf(acc[i][j][r] * s + sh, 0.f);
        out[((size_t)b * 4096 + mm) * 512 + nn] = f2bf(v);
      }
    }
  }
}

// ---------------- softmax over rows of 4096 (fp32 in, bf16 out) ----------------
__global__ __launch_bounds__(256) void softmax4096(const float* __restrict__ S, u16* __restrict__ P) {
  int row = blockIdx.x, tid = threadIdx.x;
  const float* sr = S + (size_t)row * 4096;
  f32x4 v[4];
  float mx = -3.4e38f;
#pragma unroll
  for (int i = 0; i < 4; ++i) {
    v[i] = *(const f32x4*)&sr[(i * 256 + tid) * 4];
    mx = fmaxf(mx, fmaxf(fmaxf(v[i][0], v[i][1]), fmaxf(v[i][2], v[i][3])));
  }
  __shared__ float red[8];
  int wave = tid >> 6, lane = tid & 63;
  for (int off = 32; off; off >>= 1) mx = fmaxf(mx, __shfl_xor(mx, off));
  if (lane == 0) red[wave] = mx;
  __syncthreads();
  mx = fmaxf(fmaxf(red[0], red[1]), fmaxf(red[2], red[3]));
  float sum = 0.f;
#pragma unroll
  for (int i = 0; i < 4; ++i)
#pragma unroll
    for (int j = 0; j < 4; ++j) { float e = __expf(v[i][j] - mx); v[i][j] = e; sum += e; }
  for (int off = 32; off; off >>= 1) sum += __shfl_xor(sum, off);
  if (lane == 0) red[4 + wave] = sum;
  __syncthreads();
  sum = red[4] + red[5] + red[6] + red[7];
  float inv = 1.f / sum;
  u16* pr = P + (size_t)row * 4096;
#pragma unroll
  for (int i = 0; i < 4; ++i) {
    u16x4 ov;
#pragma unroll
    for (int j = 0; j < 4; ++j) ov[j] = f2bf(v[i][j] * inv);
    *(u16x4*)&pr[(i * 256 + tid) * 4] = ov;
  }
}

// ---------------- CAM softmax: L = rowmax - S, softmax(L); rows of 512 ----------------
__global__ __launch_bounds__(256) void softmax_cam(const float* __restrict__ S, u16* __restrict__ P) {
  int row = blockIdx.x, tid = threadIdx.x;
  const float* sr = S + (size_t)row * 512;
  float a = sr[tid], b = sr[tid + 256];
  __shared__ float red[12];
  int wave = tid >> 6, lane = tid & 63;
  float mx = fmaxf(a, b);
  for (int off = 32; off; off >>= 1) mx = fmaxf(mx, __shfl_xor(mx, off));
  if (lane == 0) red[wave] = mx;
  __syncthreads();
  float M1 = fmaxf(fmaxf(red[0], red[1]), fmaxf(red[2], red[3]));
  float mn = fminf(a, b);
  for (int off = 32; off; off >>= 1) mn = fminf(mn, __shfl_xor(mn, off));
  if (lane == 0) red[4 + wave] = mn;
  __syncthreads();
  float m2 = M1 - fminf(fminf(red[4], red[5]), fminf(red[6], red[7]));
  float e0 = __expf((M1 - a) - m2), e1 = __expf((M1 - b) - m2);
  float sum = e0 + e1;
  for (int off = 32; off; off >>= 1) sum += __shfl_xor(sum, off);
  if (lane == 0) red[8 + wave] = sum;
  __syncthreads();
  sum = red[8] + red[9] + red[10] + red[11];
  float inv = 1.f / sum;
  P[(size_t)row * 512 + tid] = f2bf(e0 * inv);
  P[(size_t)row * 512 + tid + 256] = f2bf(e1 * inv);
}

// ---------------- final three 19-class 1x1 convs (writes NCHW d_out, dtype per flag) ----------------
__global__ __launch_bounds__(256) void final_out_k(const u16* __restrict__ fp2, const u16* __restrict__ fc2,
                                                   const u16* __restrict__ fv2,
                                                   const u16* ow, const u16* ob, const u16* pw,
                                                   const u16* pb, const u16* cw, const u16* cb,
                                                   void* __restrict__ out, const int* __restrict__ flag) {
  __shared__ float wl[19 * 512];
  int tid = threadIdx.x, which = blockIdx.y;
  const u16* W = which == 0 ? ow : which == 1 ? pw : cw;
  const u16* Bb = which == 0 ? ob : which == 1 ? pb : cb;
  for (int i = tid; i < 19 * 512; i += 256) wl[i] = bf2f(W[i]);
  __syncthreads();
  int pix = blockIdx.x * 256 + threadIdx.x;
  size_t rb = (size_t)pix * 512;
  float acc[19];
#pragma unroll
  for (int o = 0; o < 19; ++o) acc[o] = 0.f;
  for (int c = 0; c < 512; c += 8) {
    float xs[8];
    if (which == 0) {
      u16x8 a = *(const u16x8*)&fp2[rb + c];
      u16x8 d = *(const u16x8*)&fc2[rb + c];
      u16x8 e = *(const u16x8*)&fv2[rb + c];
#pragma unroll
      for (int j = 0; j < 8; ++j) xs[j] = bf2f(a[j]) + bf2f(d[j]) + bf2f(e[j]);
    } else {
      const u16* src = which == 1 ? fp2 : fc2;
      u16x8 a = *(const u16x8*)&src[rb + c];
#pragma unroll
      for (int j = 0; j < 8; ++j) xs[j] = bf2f(a[j]);
    }
#pragma unroll
    for (int o = 0; o < 19; ++o) {
      const float* wv = &wl[o * 512 + c];
#pragma unroll
      for (int j = 0; j < 8; ++j) acc[o] += xs[j] * wv[j];
    }
  }
  int b = pix >> 12, n = pix & 4095;
  const int isF32 = *flag;
#pragma unroll
  for (int o = 0; o < 19; ++o) {
    size_t idx = (size_t)which * 155648 + ((size_t)(b * 19 + o)) * 4096 + n;
    float v = acc[o] + bf2f(Bb[o]);
    if (isF32) ((float*)out)[idx] = v;
    else ((u16*)out)[idx] = f2bf(v);
  }
}

// ---------------- workspace layout (bytes) ----------------
static const size_t OFF_XPAD  = 0;            // 35,684,352
static const size_t OFF_WR1A  = 35684352;     // 18,874,368
static const size_t OFF_WR1B  = 54558720;     // 18,874,368
static const size_t OFF_WR1C  = 73433088;     // 18,874,368
static const size_t OFF_ARENA = 92307456;     // 33,554,432  (unused since R8; kept for layout)
static const size_t OFF_S     = 0;            // 67,108,864  (PAM overlay; phase-1 region dead)
static const size_t OFF_P     = 67108864;     // 33,554,432  (PAM overlay)
static const size_t OFF_FP1   = 125861888;    //  8,388,608
static const size_t OFF_FC1   = 134250496;    //  8,388,608
static const size_t OFF_FV1   = 142639104;    //  8,388,608
static const size_t OFF_FC1T  = 151027712;    //  8,388,608  (dead after CAM S-gemm)
static const size_t OFF_QT    = 159416320;    //  1,048,576  (dead after PAM)
static const size_t OFF_KT    = 160464896;    //  1,048,576  (dead after PAM)
static const size_t OFF_VT    = 161513472;    //  8,388,608  (dead after PAM)
static const size_t OFF_WRSA  = 151027712;    //  4,718,592  (overlay FC1T head; after CAM)
static const size_t OFF_WRSB  = 155746304;    //  4,718,592  (overlay FC1T tail + QT)
static const size_t OFF_WRSC  = 161513472;    //  4,718,592  (overlay VT)
static const size_t OFF_PADP  = 169902080;    //  8,921,088
static const size_t OFF_PADC  = 178823168;    //  8,921,088
static const size_t OFF_PADV  = 187744256;    //  8,921,088
static const size_t OFF_FP2   = 125861888;    // overlay FP1 (dead after PAM-P)
static const size_t OFF_FC2   = 134250496;    // overlay FC1 (dead after CAM)
static const size_t OFF_FV2   = 142639104;    // overlay FV1 (dead after PAM-V)
static const size_t OFF_SC    = 196665344;    //  2,097,152
static const size_t OFF_PC    = 198762496;    //  1,048,576
static const size_t OFF_BN    = 199811072;    //     24,576
static const size_t OFF_FLAG  = 199835648;    //        256
static const size_t OFF_SMALL = 199835904;    //  1,404,704
// small-block element offsets (u16):
static const size_t SO_CBN    = 0;
static const size_t SO_PWB    = 12288;
static const size_t SO_PBB    = 45056;
static const size_t SO_PWC    = 45120;
static const size_t SO_PBC    = 77888;
static const size_t SO_PWD    = 77952;
static const size_t SO_PBD    = 340096;
static const size_t SO_PAL    = 340608;
static const size_t SO_CBETA  = 340624;
static const size_t SO_VWB    = 340640;
static const size_t SO_VBB    = 373408;
static const size_t SO_VWC    = 373472;
static const size_t SO_VBC    = 406240;
static const size_t SO_VWD    = 406304;
static const size_t SO_VBD    = 668448;
static const size_t SO_VAL    = 668960;
static const size_t SO_OW     = 668976;
static const size_t SO_OB     = 678704;
static const size_t SO_PW3    = 678736;
static const size_t SO_PB3    = 688464;
static const size_t SO_CW3    = 688496;
static const size_t SO_CB3    = 698224;
static const size_t SO_LFM    = 698256;
static const size_t SO_END    = 702352;
static const size_t WS_NEEDED = OFF_SMALL + SO_END * 2;  // 201,240,608

extern "C" void kernel_launch(void* const* d_in, const int* in_sizes, int n_in,
                              void* d_out, int out_size, void* d_ws, size_t ws_size,
                              hipStream_t stream) {
  if (ws_size < WS_NEEDED) return;
  (void)in_sizes; (void)n_in; (void)out_size;

  char* ws = (char*)d_ws;
  u16* xpad   = (u16*)(ws + OFF_XPAD);
  u16* wr1a   = (u16*)(ws + OFF_WR1A);
  u16* wr1b   = (u16*)(ws + OFF_WR1B);
  u16* wr1c   = (u16*)(ws + OFF_WR1C);
  float* S    = (float*)(ws + OFF_S);
  u16* P      = (u16*)(ws + OFF_P);
  u16* fp1    = (u16*)(ws + OFF_FP1);
  u16* fc1    = (u16*)(ws + OFF_FC1);
  u16* fv1    = (u16*)(ws + OFF_FV1);
  u16* fc1T   = (u16*)(ws + OFF_FC1T);
  u16* qt     = (u16*)(ws + OFF_QT);
  u16* kt     = (u16*)(ws + OFF_KT);
  u16* vT     = (u16*)(ws + OFF_VT);
  u16* wrsa   = (u16*)(ws + OFF_WRSA);
  u16* wrsb   = (u16*)(ws + OFF_WRSB);
  u16* wrsc   = (u16*)(ws + OFF_WRSC);
  u16* padP   = (u16*)(ws + OFF_PADP);
  u16* padC   = (u16*)(ws + OFF_PADC);
  u16* padV   = (u16*)(ws + OFF_PADV);
  u16* fp2    = (u16*)(ws + OFF_FP2);
  u16* fc2    = (u16*)(ws + OFF_FC2);
  u16* fv2    = (u16*)(ws + OFF_FV2);
  float* Sc   = (float*)(ws + OFF_SC);
  u16* Pc     = (u16*)(ws + OFF_PC);
  float* bnb  = (float*)(ws + OFF_BN);
  int* flag   = (int*)(ws + OFF_FLAG);
  u16* sm     = (u16*)(ws + OFF_SMALL);

  // ---- dtype detect + canonicalize all small inputs in ONE dispatch ----
  detect_dtype<<<1, 256, 0, stream>>>((const u16*)d_in[0], flag);
  {
    CvBatch cb{};
    int jn = 0; unsigned chunks = 0;
    auto addJob = [&](int i, size_t dstOff, unsigned n) {
      cb.src[jn] = d_in[i]; cb.dstOff[jn] = (unsigned)dstOff; cb.n[jn] = n;
      cb.chunkStart[jn] = chunks; chunks += (n + 2047) / 2048; ++jn;
    };
    addJob(3,  SO_CBN + 0 * 2048, 2048);
    addJob(7,  SO_CBN + 1 * 2048, 2048);
    addJob(11, SO_CBN + 2 * 2048, 2048);
    addJob(5,  SO_CBN + 3 * 2048, 2048);
    addJob(9,  SO_CBN + 4 * 2048, 2048);
    addJob(13, SO_CBN + 5 * 2048, 2048);
    addJob(14, SO_PWB, 32768);  addJob(15, SO_PBB, 64);
    addJob(16, SO_PWC, 32768);  addJob(17, SO_PBC, 64);
    addJob(18, SO_PWD, 262144); addJob(19, SO_PBD, 512);
    addJob(20, SO_PAL, 1);      addJob(21, SO_CBETA, 1);
    addJob(22, SO_VWB, 32768);  addJob(23, SO_VBB, 64);
    addJob(24, SO_VWC, 32768);  addJob(25, SO_VBC, 64);
    addJob(26, SO_VWD, 262144); addJob(27, SO_VBD, 512);
    addJob(28, SO_VAL, 1);
    addJob(29, SO_OW, 9728);    addJob(30, SO_OB, 19);
    addJob(31, SO_PW3, 9728);   addJob(32, SO_PB3, 19);
    addJob(33, SO_CW3, 9728);   addJob(34, SO_CB3, 19);
    addJob(1,  SO_LFM, 4096);
    cb.cnt = jn; cb.chunkStart[jn] = chunks;
    convert_batch<<<chunks, 256, 0, stream>>>(cb, sm, flag);
  }

  bn_prep<<<6, 512, 0, stream>>>(sm + SO_CBN, bnb);

  // ---- x -> padded NHWC (borders zeroed border-only; interior fully written by pad) ----
  zero_border<<<dim3(260, 2), 256, 0, stream>>>(xpad, 2048);
  pad_nchw<<<dim3(32, 64, 2), 256, 0, stream>>>(d_in[0], xpad, flag);

  // ---- stage-1 weights: 3 repacks in one dispatch, then ONE fused conv dispatch ----
  {
    Repack3P rp{};
    rp.src[0] = d_in[2];  rp.dst[0] = wr1a;
    rp.src[1] = d_in[6];  rp.dst[1] = wr1b;
    rp.src[2] = d_in[10]; rp.dst[2] = wr1c;
    repack_w3<<<dim3(4608, 1, 3), 256, 0, stream>>>(rp, 2048, 11, flag);
  }
  {
    Conv3P c{};
    c.in[0] = xpad; c.in[1] = xpad; c.in[2] = xpad;
    c.wr[0] = wr1a; c.wr[1] = wr1b; c.wr[2] = wr1c;
    c.out[0] = fp1; c.out[1] = fc1; c.out[2] = fv1;
    c.bn = bnb;
    conv3x3_k<2048><<<dim3(32, 4, 6), 256, 0, stream>>>(c);
  }

  // ---- PAM (shared for pam / vfam) ----
  auto runPam = [&](const u16* src, const u16* wb, const u16* bb, const u16* wck, const u16* bck,
                    const u16* wd, const u16* bd, const u16* alphaP, const u16* rs, u16* padOut) {
    GemmP g{};
    g.A = src; g.aBatch = 2097152; g.B = wb; g.bBatch = 0; g.M = 4096; g.N = 64; g.K = 512;
    g.out = qt; g.outBatch = 262144; g.ldOut = 64; g.bias = bb; g.rowscale = rs;
    g.B2 = wck; g.bias2 = bck; g.out2 = kt;   // fused q+k: grid.z upper half does k
    gemm_nt<64, 64, 0><<<dim3(64, 1, 4), 256, 0, stream>>>(g);
    GemmP gv{};
    gv.A = src; gv.aBatch = 2097152; gv.B = wd; gv.bBatch = 0; gv.M = 4096; gv.N = 512; gv.K = 512;
    gv.out = vT; gv.outBatch = 2097152; gv.ldOut = 4096; gv.bias = bd; gv.rowscale = rs;
    gemm_nt<64, 128, 1><<<dim3(64, 4, 2), 256, 0, stream>>>(gv);
    zero_border<<<dim3(260, 2), 256, 0, stream>>>(padOut, 512);
    for (int b = 0; b < 2; ++b) {
      GemmP gs{};
      gs.A = qt + (size_t)b * 262144; gs.B = kt + (size_t)b * 262144;
      gs.M = 4096; gs.N = 4096; gs.K = 64;
      gs.outF = S; gs.outFBatch = 0; gs.ldOut = 4096;
      gemm_nt<128, 128, 2><<<dim3(32, 32, 1), 256, 0, stream>>>(gs);
      softmax4096<<<4096, 256, 0, stream>>>(S, P);
      GemmP gf{};
      gf.A = P; gf.aBatch = 0; gf.B = vT + (size_t)b * 2097152; gf.bBatch = 0;
      gf.M = 4096; gf.N = 512; gf.K = 4096;
      gf.out = padOut + (size_t)b * 2230272; gf.outBatch = 0; gf.ldOut = 512;
      gf.residual = src + (size_t)b * 2097152; gf.resBatch = 0; gf.ldRes = 512;
      gf.alphaPtr = alphaP;
      gemm_nt<128, 64, 3><<<dim3(32, 8, 1), 256, 0, stream>>>(gf);
    }
  };
  runPam(fp1, sm + SO_PWB, sm + SO_PBB, sm + SO_PWC, sm + SO_PBC, sm + SO_PWD, sm + SO_PBD,
         sm + SO_PAL, nullptr, padP);
  runPam(fv1, sm + SO_VWB, sm + SO_VBB, sm + SO_VWC, sm + SO_VBC, sm + SO_VWD, sm + SO_VBD,
         sm + SO_VAL, sm + SO_LFM, padV);

  // ---- CAM ----
  transpose64<<<dim3(64, 8, 2), 256, 0, stream>>>(fc1, fc1T, 4096, 512);
  {
    GemmP g{};
    g.A = fc1T; g.aBatch = 2097152; g.B = fc1T; g.bBatch = 2097152;
    g.M = 512; g.N = 512; g.K = 4096;
    g.outF = Sc; g.outFBatch = 262144; g.ldOut = 512;
    gemm_nt<64, 64, 2><<<dim3(8, 8, 2), 256, 0, stream>>>(g);
  }
  softmax_cam<<<1024, 256, 0, stream>>>(Sc, Pc);
  zero_border<<<dim3(260, 2), 256, 0, stream>>>(padC, 512);
  {
    GemmP g{};
    g.A = fc1; g.aBatch = 2097152; g.B = Pc; g.bBatch = 262144;
    g.M = 4096; g.N = 512; g.K = 512;
    g.out = padC; g.outBatch = 2230272; g.ldOut = 512;
    g.residual = fc1; g.resBatch = 2097152; g.ldRes = 512;
    g.alphaPtr = sm + SO_CBETA;
    gemm_nt<128, 128, 3><<<dim3(32, 4, 2), 256, 0, stream>>>(g);
  }

  // ---- stage-2 weights: 3 repacks in one dispatch, then ONE fused conv dispatch ----
  {
    Repack3P rp{};
    rp.src[0] = d_in[4];  rp.dst[0] = wrsa;
    rp.src[1] = d_in[8];  rp.dst[1] = wrsb;
    rp.src[2] = d_in[12]; rp.dst[2] = wrsc;
    repack_w3<<<dim3(1152, 1, 3), 256, 0, stream>>>(rp, 512, 9, flag);
  }
  {
    Conv3P c{};
    c.in[0] = padP; c.in[1] = padC; c.in[2] = padV;
    c.wr[0] = wrsa; c.wr[1] = wrsb; c.wr[2] = wrsc;
    c.out[0] = fp2; c.out[1] = fc2; c.out[2] = fv2;
    c.bn = bnb + 3 * 1024;
    conv3x3_k<512><<<dim3(32, 4, 6), 256, 0, stream>>>(c);
  }

  // ---- final 1x1 convs -> d_out (fusion_out, p_out, c_out) ----
  final_out_k<<<dim3(32, 3), 256, 0, stream>>>(fp2, fc2, fv2, sm + SO_OW, sm + SO_OB,
                                               sm + SO_PW3, sm + SO_PB3, sm + SO_CW3, sm + SO_CB3,
                                               d_out, flag);
}

// Round 9
// 1481.678 us; speedup vs baseline: 1.0181x; 1.0181x over previous
//
#include <hip/hip_runtime.h>

typedef unsigned short u16;
typedef short s16x8 __attribute__((ext_vector_type(8)));
typedef u16 u16x8 __attribute__((ext_vector_type(8)));
typedef u16 u16x4 __attribute__((ext_vector_type(4)));
typedef float f32x4 __attribute__((ext_vector_type(4)));

#define DEV __device__ __forceinline__

DEV float bf2f(u16 x) { unsigned v = ((unsigned)x) << 16; float f; __builtin_memcpy(&f, &v, 4); return f; }
DEV u16 f2bf(float f) { unsigned u; __builtin_memcpy(&u, &f, 4); u += 0x7FFFu + ((u >> 16) & 1u); return (u16)(u >> 16); }

// async global->LDS DMA, 16B per lane. LDS dest = wave-uniform base + lane*16.
DEV void gload16(const u16* g, u16* l) {
  __builtin_amdgcn_global_load_lds((const __attribute__((address_space(1))) void*)g,
                                   (__attribute__((address_space(3))) void*)l, 16, 0, 0);
}

// ---------------- dtype detector: bf16 data as bf16 maxes ~5; f32 data as bf16 explodes ----------------
__global__ void detect_dtype(const u16* __restrict__ x, int* __restrict__ flag) {
  int tid = threadIdx.x;
  float mx = 0.f;
  for (int i = tid; i < 4096; i += 256) mx = fmaxf(mx, fabsf(bf2f(x[i])));
  __shared__ float red[4];
  int wave = tid >> 6, lane = tid & 63;
  for (int off = 32; off; off >>= 1) mx = fmaxf(mx, __shfl_xor(mx, off));
  if (lane == 0) red[wave] = mx;
  __syncthreads();
  if (tid == 0) {
    mx = fmaxf(fmaxf(red[0], red[1]), fmaxf(red[2], red[3]));
    *flag = (mx > 1e4f) ? 1 : 0;   // 1 = inputs are float32
  }
}

// ---------------- batched small-input canonicalizer: 28 tensors in ONE dispatch ----------------
struct CvBatch {
  const void* src[28];
  unsigned dstOff[28];     // u16 units from dstBase
  unsigned n[28];          // element count
  unsigned chunkStart[29]; // prefix of ceil(n/2048)
  int cnt;
};

__global__ __launch_bounds__(256) void convert_batch(CvBatch cb, u16* __restrict__ dstBase,
                                                     const int* __restrict__ flag) {
  const int isF = *flag;
  const unsigned bid = blockIdx.x;
  int j = 0;
  while (bid >= cb.chunkStart[j + 1]) ++j;
  const unsigned base = (bid - cb.chunkStart[j]) * 2048 + threadIdx.x * 8;
  const unsigned n = cb.n[j];
  if (base >= n) return;
  u16* dst = dstBase + cb.dstOff[j];
  const void* src = cb.src[j];
  if (base + 8 <= n) {
    u16x8 v;
    if (isF) {
      const float* f = (const float*)src;
#pragma unroll
      for (int k = 0; k < 8; ++k) v[k] = f2bf(f[base + k]);
    } else {
      v = *(const u16x8*)&((const u16*)src)[base];
    }
    *(u16x8*)&dst[base] = v;
  } else {
    for (unsigned i = base; i < n; ++i)
      dst[i] = isF ? f2bf(((const float*)src)[i]) : ((const u16*)src)[i];
  }
}

// ---------------- BN prep: scale = g*rsqrt(v+eps), shift = b - m*scale ----------------
__global__ void bn_prep(const u16* __restrict__ cbn, float* __restrict__ out) {
  int w = blockIdx.x;
  const u16* bn = cbn + w * 2048;
  int c = threadIdx.x;
  float g = bf2f(bn[c]), be = bf2f(bn[512 + c]), m = bf2f(bn[1024 + c]), v = bf2f(bn[1536 + c]);
  float sc = g * rsqrtf(v + 1e-5f);
  out[w * 1024 + c] = sc;
  out[w * 1024 + 512 + c] = be - m * sc;
}

// ---------------- weight repack (O,I,3,3) -> (O,3,3,I), 3 weight sets per dispatch (grid.z) ----------------
struct Repack3P { const void* src[3]; u16* dst[3]; };

__global__ __launch_bounds__(256) void repack_w3(Repack3P rp, int I, int Ishift,
                                                 const int* __restrict__ flag) {
  const int isF = *flag;
  const void* w = rp.src[blockIdx.z];
  u16* wr = rp.dst[blockIdx.z];
  size_t idx = ((size_t)blockIdx.x * 256 + threadIdx.x) * 8;
  int i0 = (int)(idx & (size_t)(I - 1));
  int t = (int)(idx >> Ishift);
  int o = t / 9, kk = t - o * 9;
  u16x8 v;
  if (isF) {
    const float* f = (const float*)w;
#pragma unroll
    for (int j = 0; j < 8; ++j) v[j] = f2bf(f[((size_t)o * I + i0 + j) * 9 + kk]);
  } else {
    const u16* bsrc = (const u16*)w;
#pragma unroll
    for (int j = 0; j < 8; ++j) v[j] = bsrc[((size_t)o * I + i0 + j) * 9 + kk];
  }
  *(u16x8*)&wr[idx] = v;
}

// ---------------- border-only zeroing of a padded (B,66,66,CIN) NHWC buffer ----------------
__global__ __launch_bounds__(256) void zero_border(u16* __restrict__ base, int CIN) {
  int p = blockIdx.x, b = blockIdx.y;
  int py, px;
  if (p < 66)       { py = 0;        px = p; }
  else if (p < 132) { py = 65;       px = p - 66; }
  else if (p < 196) { py = p - 131;  px = 0; }    // py 1..64
  else              { py = p - 195;  px = 65; }   // py 1..64
  u16* d = base + (((size_t)b * 66 + py) * 66 + px) * (size_t)CIN;
  for (int i = threadIdx.x * 8; i < CIN; i += 2048) {
    u16x8 z;
#pragma unroll
    for (int k = 0; k < 8; ++k) z[k] = 0;
    *(u16x8*)&d[i] = z;
  }
}

// ---------------- x NCHW -> padded NHWC (B,66,66,2048), borders pre-zeroed; raw input ----------------
__global__ __launch_bounds__(256) void pad_nchw(const void* __restrict__ x, u16* __restrict__ xpad,
                                                const int* __restrict__ flag) {
  __shared__ u16 t[64][72];
  const int isF = *flag;
  int c0 = blockIdx.x * 64, h = blockIdx.y, b = blockIdx.z;
  int tid = threadIdx.x;
#pragma unroll
  for (int i = 0; i < 2; ++i) {
    int idx = i * 256 + tid;
    int cc = idx >> 3, ww = (idx & 7) * 8;
    size_t base = (((size_t)(b * 2048 + c0 + cc) * 64) + h) * 64 + ww;
    u16x8 v;
    if (isF) {
      const float* fx = (const float*)x;
#pragma unroll
      for (int j = 0; j < 8; ++j) v[j] = f2bf(fx[base + j]);
    } else {
      v = *(const u16x8*)&((const u16*)x)[base];
    }
    *(u16x8*)&t[cc][ww] = v;
  }
  __syncthreads();
#pragma unroll
  for (int i = 0; i < 2; ++i) {
    int idx = i * 256 + tid;
    int ww = idx >> 3, cc = (idx & 7) * 8;
    u16x8 v;
#pragma unroll
    for (int j = 0; j < 8; ++j) v[j] = t[cc + j][ww];
    *(u16x8*)&xpad[(((size_t)b * 66 + h + 1) * 66 + ww + 1) * 2048 + c0 + cc] = v;
  }
}

// ---------------- generic bf16 transpose (R,C)->(C,R) per batch ----------------
__global__ __launch_bounds__(256) void transpose64(const u16* __restrict__ src, u16* __restrict__ dst,
                                                   int R, int C) {
  __shared__ u16 t[64][72];
  int r0 = blockIdx.x * 64, c0 = blockIdx.y * 64;
  const u16* s = src + (size_t)blockIdx.z * R * C;
  u16* d = dst + (size_t)blockIdx.z * R * C;
  int tid = threadIdx.x;
#pragma unroll
  for (int i = 0; i < 2; ++i) {
    int idx = i * 256 + tid;
    int rr = idx >> 3, cc = (idx & 7) * 8;
    u16x8 v = *(const u16x8*)&s[(size_t)(r0 + rr) * C + c0 + cc];
    *(u16x8*)&t[rr][cc] = v;
  }
  __syncthreads();
#pragma unroll
  for (int i = 0; i < 2; ++i) {
    int idx = i * 256 + tid;
    int cc = idx >> 3, rr = (idx & 7) * 8;
    u16x8 v;
#pragma unroll
    for (int j = 0; j < 8; ++j) v[j] = t[rr + j][cc];
    *(u16x8*)&d[(size_t)(c0 + cc) * R + r0 + rr] = v;
  }
}

// ---------------- unified NT GEMM: C[m,n] = sum_k A[m,k]*B[n,k] ----------------
// R12 (kept): 2-phase double-buffer — stage tile k+1 BEFORE computing tile k. BK=32, 2 buffers.
// R8 A/B: this helped the gemms (~30us aggregate) while the same structure HURT the conv
// (16 MFMA can't cover the drain; conv reverted to BK=64 2-barrier — see conv3x3_k).
// EPI: 0 = bf16 store (+bias, *rowscale; optional fused 2nd problem via B2/bias2/out2)
//      1 = bf16 transposed store ; 2 = fp32 store (LDS-bounced f32x4) ; 3 = alpha*acc+residual -> padded NHWC
// Requires K % 32 == 0.
struct GemmP {
  const u16* A; const u16* B;
  long aBatch, bBatch;
  int M, N, K;
  u16* out; long outBatch; int ldOut;
  const u16* bias;
  const u16* rowscale;
  const u16* residual; long resBatch; int ldRes;
  const u16* alphaPtr;
  float* outF; long outFBatch;
  const u16* B2; const u16* bias2; u16* out2;
};

template <int BM, int BN, int EPI>
__global__ __launch_bounds__(256) void gemm_nt(GemmP p) {
  static_assert(EPI != 2 || BM >= BN, "EPI2 LDS bounce needs BM>=BN");
  constexpr int HB = (BM + BN) * 32;   // u16 per buffer (A tile then B tile)
  __shared__ __align__(16) u16 ls[2][HB];
  const int tid = threadIdx.x;
  int bz = blockIdx.z;
  const u16* Bsel = p.B;
  const u16* biasSel = p.bias;
  u16* outSel = p.out;
  if (EPI == 0 && p.out2) {
    const int h = gridDim.z >> 1;
    if (bz >= h) { bz -= h; Bsel = p.B2; biasSel = p.bias2; outSel = p.out2; }
  }
  const int m0 = blockIdx.x * BM, n0 = blockIdx.y * BN;
  const u16* A = p.A + (size_t)bz * p.aBatch;
  const u16* Bp = Bsel + (size_t)bz * p.bBatch;
  const int wave = tid >> 6, lane = tid & 63;
  const int quad = lane >> 4, r16 = lane & 15;
  const int wm = (wave >> 1) * (BM / 2), wn = (wave & 1) * (BN / 2);
  constexpr int TM = BM / 32, TN = BN / 32;
  f32x4 acc[TM][TN] = {};
  const int srow = tid >> 2, sch = (tid & 3) * 8;
  const int K = p.K;
  auto stage = [&](int buf, int k0) {
#pragma unroll
    for (int i = 0; i < BM / 64; ++i)
      gload16(&A[(size_t)(m0 + i * 64 + srow) * K + k0 + sch], &ls[buf][i * 2048 + wave * 512]);
#pragma unroll
    for (int i = 0; i < BN / 64; ++i)
      gload16(&Bp[(size_t)(n0 + i * 64 + srow) * K + k0 + sch],
              &ls[buf][BM * 32 + i * 2048 + wave * 512]);
  };
  stage(0, 0);
  __syncthreads();  // vmcnt(0) drain: buffer 0 ready
  int cur = 0;
  for (int k0 = 0; k0 < K; k0 += 32) {
    if (k0 + 32 < K) stage(cur ^ 1, k0 + 32);   // issue next tile; drained at THIS iter's barrier
    const u16* lA = &ls[cur][0];
    const u16* lB = &ls[cur][BM * 32];
    s16x8 av[TM], bv[TN];
#pragma unroll
    for (int t = 0; t < TM; ++t) av[t] = *(const s16x8*)&lA[(wm + t * 16 + r16) * 32 + quad * 8];
#pragma unroll
    for (int t = 0; t < TN; ++t) bv[t] = *(const s16x8*)&lB[(wn + t * 16 + r16) * 32 + quad * 8];
#pragma unroll
    for (int i = 0; i < TM; ++i)
#pragma unroll
      for (int j = 0; j < TN; ++j)
        acc[i][j] = __builtin_amdgcn_mfma_f32_16x16x32_bf16(av[i], bv[j], acc[i][j], 0, 0, 0);
    __syncthreads();  // all reads of ls[cur] done + next-tile staging drained
    cur ^= 1;
  }
  if constexpr (EPI == 2) {
    // LDS-bounced vector stores: per i, this block's 32 rows x BN cols go through LDS fp32,
    // then read back row-major and stored f32x4 (256B segments vs 64B scalar).
    float* lsF = (float*)&ls[0][0];   // capacity (BM+BN)*128 B >= 32*BN*4 B
#pragma unroll
    for (int i = 0; i < TM; ++i) {
      __syncthreads();
#pragma unroll
      for (int j = 0; j < TN; ++j) {
        const int col = wn + j * 16 + r16;
#pragma unroll
        for (int r = 0; r < 4; ++r) {
          const int rowL = (wave >> 1) * 16 + quad * 4 + r;
          lsF[rowL * BN + col] = acc[i][j][r];
        }
      }
      __syncthreads();
      constexpr int PASSES = (32 * BN) / 1024;
#pragma unroll
      for (int pp = 0; pp < PASSES; ++pp) {
        const int lin = (pp * 256 + tid) * 4;
        const int rowL = lin / BN, col = lin & (BN - 1);
        const int gm = m0 + (rowL >> 4) * (BM / 2) + i * 16 + (rowL & 15);
        *(f32x4*)&p.outF[(size_t)bz * p.outFBatch + (size_t)gm * p.ldOut + (n0 + col)] =
            *(const f32x4*)&lsF[lin];
      }
    }
    return;
  }
  float alpha = 0.f;
  if (EPI == 3) alpha = bf2f(p.alphaPtr[0]);
#pragma unroll
  for (int i = 0; i < TM; ++i) {
#pragma unroll
    for (int j = 0; j < TN; ++j) {
      const int nn = n0 + wn + j * 16 + r16;
      float bia = 0.f;
      if ((EPI == 0 || EPI == 1) && biasSel) bia = bf2f(biasSel[nn]);
#pragma unroll
      for (int r = 0; r < 4; ++r) {
        const int mm = m0 + wm + i * 16 + quad * 4 + r;
        float v = acc[i][j][r];
        if (EPI == 0) {
          v += bia;
          if (p.rowscale) v *= bf2f(p.rowscale[mm]);
          outSel[(size_t)bz * p.outBatch + (size_t)mm * p.ldOut + nn] = f2bf(v);
        } else if (EPI == 1) {
          v += bia;
          if (p.rowscale) v *= bf2f(p.rowscale[mm]);
          p.out[(size_t)bz * p.outBatch + (size_t)nn * p.ldOut + mm] = f2bf(v);
        } else {
          float res = bf2f(p.residual[(size_t)bz * p.resBatch + (size_t)mm * p.ldRes + nn]);
          v = alpha * v + res;
          const int py = mm >> 6, px = mm & 63;
          p.out[(size_t)bz * p.outBatch + ((size_t)(py + 1) * 66 + (px + 1)) * p.ldOut + nn] = f2bf(v);
        }
      }
    }
  }
}

// ---------------- fused 3-conv 3x3 (implicit GEMM) + BN + ReLU, NHWC padded input ----------------
// blockIdx.z in [0,6): ci = z>>1 selects conv (input/weights/output), b = z&1 batch.
// R13: REVERTED to the R7/R11 structure (measured 461us, MfmaUtil 46.9%) — BK=64, c-chunk
// outer / 9-tap inner (L2-hot A re-reads), 2 barriers per 64-k, 32 KB LDS. R8's 2-phase dbuf
// at BK=32 regressed this kernel (-35us): the barrier's vmcnt(0) drains the just-issued
// next-tile loads, and 16 MFMA/iter can't cover the latency while loop overhead doubles.
struct Conv3P {
  const u16* in[3];
  const u16* wr[3];
  u16* out[3];
  const float* bn;   // conv ci: scale = bn[ci*1024 + n], shift = bn[ci*1024 + 512 + n]
};

template <int CIN>
__global__ __launch_bounds__(256) void conv3x3_k(Conv3P p) {
  __shared__ u16 lA[8192], lB[8192];
  const int tid = threadIdx.x;
  const int z = blockIdx.z, ci = z >> 1, b = z & 1;
  const int m0 = blockIdx.x * 128, n0 = blockIdx.y * 128;
  const u16* __restrict__ xin = p.in[ci];
  const u16* __restrict__ wr = p.wr[ci];
  const int wave = tid >> 6, lane = tid & 63;
  const int quad = lane >> 4, r16 = lane & 15;
  const int wm = (wave >> 1) * 64, wn = (wave & 1) * 64;
  f32x4 acc[4][4] = {};
  const int srow = tid >> 2, sch = (tid & 3) * 8;
  const int p0 = m0 + srow, p1 = p0 + 64;
  const size_t a0 = (((size_t)b * 66 + (p0 >> 6)) * 66 + (p0 & 63)) * CIN + sch;
  const size_t a1 = (((size_t)b * 66 + (p1 >> 6)) * 66 + (p1 & 63)) * CIN + sch;
  const size_t b0 = ((size_t)(n0 + srow) * 9) * CIN + sch;
  const size_t b1 = ((size_t)(n0 + 64 + srow) * 9) * CIN + sch;
  // wave-uniform LDS bases: rows 0-63 k-lo, rows 64-127 k-lo, rows 0-63 k-hi, rows 64-127 k-hi
  u16* la0 = &lA[wave * 512];
  u16* la1 = &lA[2048 + wave * 512];
  u16* la2 = &lA[4096 + wave * 512];
  u16* la3 = &lA[6144 + wave * 512];
  u16* lb0 = &lB[wave * 512];
  u16* lb1 = &lB[2048 + wave * 512];
  u16* lb2 = &lB[4096 + wave * 512];
  u16* lb3 = &lB[6144 + wave * 512];
  for (int c = 0; c < CIN; c += 64) {
    for (int kh = 0; kh < 3; ++kh) {
      for (int kw = 0; kw < 3; ++kw) {
        const size_t soff = ((size_t)kh * 66 + kw) * CIN + c;
        const size_t woff = (size_t)(kh * 3 + kw) * CIN + c;
        __syncthreads();
        gload16(&xin[a0 + soff], la0);
        gload16(&xin[a1 + soff], la1);
        gload16(&xin[a0 + soff + 32], la2);
        gload16(&xin[a1 + soff + 32], la3);
        gload16(&wr[b0 + woff], lb0);
        gload16(&wr[b1 + woff], lb1);
        gload16(&wr[b0 + woff + 32], lb2);
        gload16(&wr[b1 + woff + 32], lb3);
        __syncthreads();  // compiler emits vmcnt(0) drain -> both 32-k subtiles ready
#pragma unroll
        for (int q = 0; q < 2; ++q) {
          s16x8 av[4], bv[4];
#pragma unroll
          for (int t = 0; t < 4; ++t)
            av[t] = *(const s16x8*)&lA[q * 4096 + (wm + t * 16 + r16) * 32 + quad * 8];
#pragma unroll
          for (int t = 0; t < 4; ++t)
            bv[t] = *(const s16x8*)&lB[q * 4096 + (wn + t * 16 + r16) * 32 + quad * 8];
#pragma unroll
          for (int i = 0; i < 4; ++i)
#pragma unroll
            for (int j = 0; j < 4; ++j)
              acc[i][j] = __builtin_amdgcn_mfma_f32_16x16x32_bf16(av[i], bv[j], acc[i][j], 0, 0, 0);
        }
      }
    }
  }
  u16* __restrict__ out = p.out[ci];
  const float* bnS = p.bn + ci * 1024;
#pragma unroll
  for (int i = 0; i < 4; ++i) {
#pragma unroll
    for (int j = 0; j < 4; ++j) {
      const int nn = n0 + wn + j * 16 + r16;
      const float s = bnS[nn], sh = bnS[512 + nn];
#pragma unroll
      for (int r = 0; r < 4; ++r) {
        const int mm = m0 + wm + i * 16 + quad * 4 + r;
        float v = fmaxf(acc[i][j][r] * s + sh, 0.f);
        out[((size_t)b * 4096 + mm) * 512 + nn] = f2bf(v);
      }
    }
  }
}

// ---------------- softmax over rows of 4096 (fp32 in, bf16 out) ----------------
__global__ __launch_bounds__(256) void softmax4096(const float* __restrict__ S, u16* __restrict__ P) {
  int row = blockIdx.x, tid = threadIdx.x;
  const float* sr = S + (size_t)row * 4096;
  f32x4 v[4];
  float mx = -3.4e38f;
#pragma unroll
  for (int i = 0; i < 4; ++i) {
    v[i] = *(const f32x4*)&sr[(i * 256 + tid) * 4];
    mx = fmaxf(mx, fmaxf(fmaxf(v[i][0], v[i][1]), fmaxf(v[i][2], v[i][3])));
  }
  __shared__ float red[8];
  int wave = tid >> 6, lane = tid & 63;
  for (int off = 32; off; off >>= 1) mx = fmaxf(mx, __shfl_xor(mx, off));
  if (lane == 0) red[wave] = mx;
  __syncthreads();
  mx = fmaxf(fmaxf(red[0], red[1]), fmaxf(red[2], red[3]));
  float sum = 0.f;
#pragma unroll
  for (int i = 0; i < 4; ++i)
#pragma unroll
    for (int j = 0; j < 4; ++j) { float e = __expf(v[i][j] - mx); v[i][j] = e; sum += e; }
  for (int off = 32; off; off >>= 1) sum += __shfl_xor(sum, off);
  if (lane == 0) red[4 + wave] = sum;
  __syncthreads();
  sum = red[4] + red[5] + red[6] + red[7];
  float inv = 1.f / sum;
  u16* pr = P + (size_t)row * 4096;
#pragma unroll
  for (int i = 0; i < 4; ++i) {
    u16x4 ov;
#pragma unroll
    for (int j = 0; j < 4; ++j) ov[j] = f2bf(v[i][j] * inv);
    *(u16x4*)&pr[(i * 256 + tid) * 4] = ov;
  }
}

// ---------------- CAM softmax: L = rowmax - S, softmax(L); rows of 512 ----------------
__global__ __launch_bounds__(256) void softmax_cam(const float* __restrict__ S, u16* __restrict__ P) {
  int row = blockIdx.x, tid = threadIdx.x;
  const float* sr = S + (size_t)row * 512;
  float a = sr[tid], b = sr[tid + 256];
  __shared__ float red[12];
  int wave = tid >> 6, lane = tid & 63;
  float mx = fmaxf(a, b);
  for (int off = 32; off; off >>= 1) mx = fmaxf(mx, __shfl_xor(mx, off));
  if (lane == 0) red[wave] = mx;
  __syncthreads();
  float M1 = fmaxf(fmaxf(red[0], red[1]), fmaxf(red[2], red[3]));
  float mn = fminf(a, b);
  for (int off = 32; off; off >>= 1) mn = fminf(mn, __shfl_xor(mn, off));
  if (lane == 0) red[4 + wave] = mn;
  __syncthreads();
  float m2 = M1 - fminf(fminf(red[4], red[5]), fminf(red[6], red[7]));
  float e0 = __expf((M1 - a) - m2), e1 = __expf((M1 - b) - m2);
  float sum = e0 + e1;
  for (int off = 32; off; off >>= 1) sum += __shfl_xor(sum, off);
  if (lane == 0) red[8 + wave] = sum;
  __syncthreads();
  sum = red[8] + red[9] + red[10] + red[11];
  float inv = 1.f / sum;
  P[(size_t)row * 512 + tid] = f2bf(e0 * inv);
  P[(size_t)row * 512 + tid + 256] = f2bf(e1 * inv);
}

// ---------------- final three 19-class 1x1 convs (writes NCHW d_out, dtype per flag) ----------------
__global__ __launch_bounds__(256) void final_out_k(const u16* __restrict__ fp2, const u16* __restrict__ fc2,
                                                   const u16* __restrict__ fv2,
                                                   const u16* ow, const u16* ob, const u16* pw,
                                                   const u16* pb, const u16* cw, const u16* cb,
                                                   void* __restrict__ out, const int* __restrict__ flag) {
  __shared__ float wl[19 * 512];
  int tid = threadIdx.x, which = blockIdx.y;
  const u16* W = which == 0 ? ow : which == 1 ? pw : cw;
  const u16* Bb = which == 0 ? ob : which == 1 ? pb : cb;
  for (int i = tid; i < 19 * 512; i += 256) wl[i] = bf2f(W[i]);
  __syncthreads();
  int pix = blockIdx.x * 256 + threadIdx.x;
  size_t rb = (size_t)pix * 512;
  float acc[19];
#pragma unroll
  for (int o = 0; o < 19; ++o) acc[o] = 0.f;
  for (int c = 0; c < 512; c += 8) {
    float xs[8];
    if (which == 0) {
      u16x8 a = *(const u16x8*)&fp2[rb + c];
      u16x8 d = *(const u16x8*)&fc2[rb + c];
      u16x8 e = *(const u16x8*)&fv2[rb + c];
#pragma unroll
      for (int j = 0; j < 8; ++j) xs[j] = bf2f(a[j]) + bf2f(d[j]) + bf2f(e[j]);
    } else {
      const u16* src = which == 1 ? fp2 : fc2;
      u16x8 a = *(const u16x8*)&src[rb + c];
#pragma unroll
      for (int j = 0; j < 8; ++j) xs[j] = bf2f(a[j]);
    }
#pragma unroll
    for (int o = 0; o < 19; ++o) {
      const float* wv = &wl[o * 512 + c];
#pragma unroll
      for (int j = 0; j < 8; ++j) acc[o] += xs[j] * wv[j];
    }
  }
  int b = pix >> 12, n = pix & 4095;
  const int isF32 = *flag;
#pragma unroll
  for (int o = 0; o < 19; ++o) {
    size_t idx = (size_t)which * 155648 + ((size_t)(b * 19 + o)) * 4096 + n;
    float v = acc[o] + bf2f(Bb[o]);
    if (isF32) ((float*)out)[idx] = v;
    else ((u16*)out)[idx] = f2bf(v);
  }
}

// ---------------- workspace layout (bytes) ----------------
static const size_t OFF_XPAD  = 0;            // 35,684,352
static const size_t OFF_WR1A  = 35684352;     // 18,874,368
static const size_t OFF_WR1B  = 54558720;     // 18,874,368
static const size_t OFF_WR1C  = 73433088;     // 18,874,368
static const size_t OFF_ARENA = 92307456;     // 33,554,432  (unused since R8; kept for layout)
static const size_t OFF_S     = 0;            // 67,108,864  (PAM overlay; phase-1 region dead)
static const size_t OFF_P     = 67108864;     // 33,554,432  (PAM overlay)
static const size_t OFF_FP1   = 125861888;    //  8,388,608
static const size_t OFF_FC1   = 134250496;    //  8,388,608
static const size_t OFF_FV1   = 142639104;    //  8,388,608
static const size_t OFF_FC1T  = 151027712;    //  8,388,608  (dead after CAM S-gemm)
static const size_t OFF_QT    = 159416320;    //  1,048,576  (dead after PAM)
static const size_t OFF_KT    = 160464896;    //  1,048,576  (dead after PAM)
static const size_t OFF_VT    = 161513472;    //  8,388,608  (dead after PAM)
static const size_t OFF_WRSA  = 151027712;    //  4,718,592  (overlay FC1T head; after CAM)
static const size_t OFF_WRSB  = 155746304;    //  4,718,592  (overlay FC1T tail + QT)
static const size_t OFF_WRSC  = 161513472;    //  4,718,592  (overlay VT)
static const size_t OFF_PADP  = 169902080;    //  8,921,088
static const size_t OFF_PADC  = 178823168;    //  8,921,088
static const size_t OFF_PADV  = 187744256;    //  8,921,088
static const size_t OFF_FP2   = 125861888;    // overlay FP1 (dead after PAM-P)
static const size_t OFF_FC2   = 134250496;    // overlay FC1 (dead after CAM)
static const size_t OFF_FV2   = 142639104;    // overlay FV1 (dead after PAM-V)
static const size_t OFF_SC    = 196665344;    //  2,097,152
static const size_t OFF_PC    = 198762496;    //  1,048,576
static const size_t OFF_BN    = 199811072;    //     24,576
static const size_t OFF_FLAG  = 199835648;    //        256
static const size_t OFF_SMALL = 199835904;    //  1,404,704
// small-block element offsets (u16):
static const size_t SO_CBN    = 0;
static const size_t SO_PWB    = 12288;
static const size_t SO_PBB    = 45056;
static const size_t SO_PWC    = 45120;
static const size_t SO_PBC    = 77888;
static const size_t SO_PWD    = 77952;
static const size_t SO_PBD    = 340096;
static const size_t SO_PAL    = 340608;
static const size_t SO_CBETA  = 340624;
static const size_t SO_VWB    = 340640;
static const size_t SO_VBB    = 373408;
static const size_t SO_VWC    = 373472;
static const size_t SO_VBC    = 406240;
static const size_t SO_VWD    = 406304;
static const size_t SO_VBD    = 668448;
static const size_t SO_VAL    = 668960;
static const size_t SO_OW     = 668976;
static const size_t SO_OB     = 678704;
static const size_t SO_PW3    = 678736;
static const size_t SO_PB3    = 688464;
static const size_t SO_CW3    = 688496;
static const size_t SO_CB3    = 698224;
static const size_t SO_LFM    = 698256;
static const size_t SO_END    = 702352;
static const size_t WS_NEEDED = OFF_SMALL + SO_END * 2;  // 201,240,608

extern "C" void kernel_launch(void* const* d_in, const int* in_sizes, int n_in,
                              void* d_out, int out_size, void* d_ws, size_t ws_size,
                              hipStream_t stream) {
  if (ws_size < WS_NEEDED) return;
  (void)in_sizes; (void)n_in; (void)out_size;

  char* ws = (char*)d_ws;
  u16* xpad   = (u16*)(ws + OFF_XPAD);
  u16* wr1a   = (u16*)(ws + OFF_WR1A);
  u16* wr1b   = (u16*)(ws + OFF_WR1B);
  u16* wr1c   = (u16*)(ws + OFF_WR1C);
  float* S    = (float*)(ws + OFF_S);
  u16* P      = (u16*)(ws + OFF_P);
  u16* fp1    = (u16*)(ws + OFF_FP1);
  u16* fc1    = (u16*)(ws + OFF_FC1);
  u16* fv1    = (u16*)(ws + OFF_FV1);
  u16* fc1T   = (u16*)(ws + OFF_FC1T);
  u16* qt     = (u16*)(ws + OFF_QT);
  u16* kt     = (u16*)(ws + OFF_KT);
  u16* vT     = (u16*)(ws + OFF_VT);
  u16* wrsa   = (u16*)(ws + OFF_WRSA);
  u16* wrsb   = (u16*)(ws + OFF_WRSB);
  u16* wrsc   = (u16*)(ws + OFF_WRSC);
  u16* padP   = (u16*)(ws + OFF_PADP);
  u16* padC   = (u16*)(ws + OFF_PADC);
  u16* padV   = (u16*)(ws + OFF_PADV);
  u16* fp2    = (u16*)(ws + OFF_FP2);
  u16* fc2    = (u16*)(ws + OFF_FC2);
  u16* fv2    = (u16*)(ws + OFF_FV2);
  float* Sc   = (float*)(ws + OFF_SC);
  u16* Pc     = (u16*)(ws + OFF_PC);
  float* bnb  = (float*)(ws + OFF_BN);
  int* flag   = (int*)(ws + OFF_FLAG);
  u16* sm     = (u16*)(ws + OFF_SMALL);

  // ---- dtype detect + canonicalize all small inputs in ONE dispatch ----
  detect_dtype<<<1, 256, 0, stream>>>((const u16*)d_in[0], flag);
  {
    CvBatch cb{};
    int jn = 0; unsigned chunks = 0;
    auto addJob = [&](int i, size_t dstOff, unsigned n) {
      cb.src[jn] = d_in[i]; cb.dstOff[jn] = (unsigned)dstOff; cb.n[jn] = n;
      cb.chunkStart[jn] = chunks; chunks += (n + 2047) / 2048; ++jn;
    };
    addJob(3,  SO_CBN + 0 * 2048, 2048);
    addJob(7,  SO_CBN + 1 * 2048, 2048);
    addJob(11, SO_CBN + 2 * 2048, 2048);
    addJob(5,  SO_CBN + 3 * 2048, 2048);
    addJob(9,  SO_CBN + 4 * 2048, 2048);
    addJob(13, SO_CBN + 5 * 2048, 2048);
    addJob(14, SO_PWB, 32768);  addJob(15, SO_PBB, 64);
    addJob(16, SO_PWC, 32768);  addJob(17, SO_PBC, 64);
    addJob(18, SO_PWD, 262144); addJob(19, SO_PBD, 512);
    addJob(20, SO_PAL, 1);      addJob(21, SO_CBETA, 1);
    addJob(22, SO_VWB, 32768);  addJob(23, SO_VBB, 64);
    addJob(24, SO_VWC, 32768);  addJob(25, SO_VBC, 64);
    addJob(26, SO_VWD, 262144); addJob(27, SO_VBD, 512);
    addJob(28, SO_VAL, 1);
    addJob(29, SO_OW, 9728);    addJob(30, SO_OB, 19);
    addJob(31, SO_PW3, 9728);   addJob(32, SO_PB3, 19);
    addJob(33, SO_CW3, 9728);   addJob(34, SO_CB3, 19);
    addJob(1,  SO_LFM, 4096);
    cb.cnt = jn; cb.chunkStart[jn] = chunks;
    convert_batch<<<chunks, 256, 0, stream>>>(cb, sm, flag);
  }

  bn_prep<<<6, 512, 0, stream>>>(sm + SO_CBN, bnb);

  // ---- x -> padded NHWC (borders zeroed border-only; interior fully written by pad) ----
  zero_border<<<dim3(260, 2), 256, 0, stream>>>(xpad, 2048);
  pad_nchw<<<dim3(32, 64, 2), 256, 0, stream>>>(d_in[0], xpad, flag);

  // ---- stage-1 weights: 3 repacks in one dispatch, then ONE fused conv dispatch ----
  {
    Repack3P rp{};
    rp.src[0] = d_in[2];  rp.dst[0] = wr1a;
    rp.src[1] = d_in[6];  rp.dst[1] = wr1b;
    rp.src[2] = d_in[10]; rp.dst[2] = wr1c;
    repack_w3<<<dim3(4608, 1, 3), 256, 0, stream>>>(rp, 2048, 11, flag);
  }
  {
    Conv3P c{};
    c.in[0] = xpad; c.in[1] = xpad; c.in[2] = xpad;
    c.wr[0] = wr1a; c.wr[1] = wr1b; c.wr[2] = wr1c;
    c.out[0] = fp1; c.out[1] = fc1; c.out[2] = fv1;
    c.bn = bnb;
    conv3x3_k<2048><<<dim3(32, 4, 6), 256, 0, stream>>>(c);
  }

  // ---- PAM (shared for pam / vfam) ----
  auto runPam = [&](const u16* src, const u16* wb, const u16* bb, const u16* wck, const u16* bck,
                    const u16* wd, const u16* bd, const u16* alphaP, const u16* rs, u16* padOut) {
    GemmP g{};
    g.A = src; g.aBatch = 2097152; g.B = wb; g.bBatch = 0; g.M = 4096; g.N = 64; g.K = 512;
    g.out = qt; g.outBatch = 262144; g.ldOut = 64; g.bias = bb; g.rowscale = rs;
    g.B2 = wck; g.bias2 = bck; g.out2 = kt;   // fused q+k: grid.z upper half does k
    gemm_nt<64, 64, 0><<<dim3(64, 1, 4), 256, 0, stream>>>(g);
    GemmP gv{};
    gv.A = src; gv.aBatch = 2097152; gv.B = wd; gv.bBatch = 0; gv.M = 4096; gv.N = 512; gv.K = 512;
    gv.out = vT; gv.outBatch = 2097152; gv.ldOut = 4096; gv.bias = bd; gv.rowscale = rs;
    gemm_nt<64, 128, 1><<<dim3(64, 4, 2), 256, 0, stream>>>(gv);
    zero_border<<<dim3(260, 2), 256, 0, stream>>>(padOut, 512);
    for (int b = 0; b < 2; ++b) {
      GemmP gs{};
      gs.A = qt + (size_t)b * 262144; gs.B = kt + (size_t)b * 262144;
      gs.M = 4096; gs.N = 4096; gs.K = 64;
      gs.outF = S; gs.outFBatch = 0; gs.ldOut = 4096;
      gemm_nt<128, 128, 2><<<dim3(32, 32, 1), 256, 0, stream>>>(gs);
      softmax4096<<<4096, 256, 0, stream>>>(S, P);
      GemmP gf{};
      gf.A = P; gf.aBatch = 0; gf.B = vT + (size_t)b * 2097152; gf.bBatch = 0;
      gf.M = 4096; gf.N = 512; gf.K = 4096;
      gf.out = padOut + (size_t)b * 2230272; gf.outBatch = 0; gf.ldOut = 512;
      gf.residual = src + (size_t)b * 2097152; gf.resBatch = 0; gf.ldRes = 512;
      gf.alphaPtr = alphaP;
      gemm_nt<128, 64, 3><<<dim3(32, 8, 1), 256, 0, stream>>>(gf);
    }
  };
  runPam(fp1, sm + SO_PWB, sm + SO_PBB, sm + SO_PWC, sm + SO_PBC, sm + SO_PWD, sm + SO_PBD,
         sm + SO_PAL, nullptr, padP);
  runPam(fv1, sm + SO_VWB, sm + SO_VBB, sm + SO_VWC, sm + SO_VBC, sm + SO_VWD, sm + SO_VBD,
         sm + SO_VAL, sm + SO_LFM, padV);

  // ---- CAM ----
  transpose64<<<dim3(64, 8, 2), 256, 0, stream>>>(fc1, fc1T, 4096, 512);
  {
    GemmP g{};
    g.A = fc1T; g.aBatch = 2097152; g.B = fc1T; g.bBatch = 2097152;
    g.M = 512; g.N = 512; g.K = 4096;
    g.outF = Sc; g.outFBatch = 262144; g.ldOut = 512;
    gemm_nt<64, 64, 2><<<dim3(8, 8, 2), 256, 0, stream>>>(g);
  }
  softmax_cam<<<1024, 256, 0, stream>>>(Sc, Pc);
  zero_border<<<dim3(260, 2), 256, 0, stream>>>(padC, 512);
  {
    GemmP g{};
    g.A = fc1; g.aBatch = 2097152; g.B = Pc; g.bBatch = 262144;
    g.M = 4096; g.N = 512; g.K = 512;
    g.out = padC; g.outBatch = 2230272; g.ldOut = 512;
    g.residual = fc1; g.resBatch = 2097152; g.ldRes = 512;
    g.alphaPtr = sm + SO_CBETA;
    gemm_nt<128, 128, 3><<<dim3(32, 4, 2), 256, 0, stream>>>(g);
  }

  // ---- stage-2 weights: 3 repacks in one dispatch, then ONE fused conv dispatch ----
  {
    Repack3P rp{};
    rp.src[0] = d_in[4];  rp.dst[0] = wrsa;
    rp.src[1] = d_in[8];  rp.dst[1] = wrsb;
    rp.src[2] = d_in[12]; rp.dst[2] = wrsc;
    repack_w3<<<dim3(1152, 1, 3), 256, 0, stream>>>(rp, 512, 9, flag);
  }
  {
    Conv3P c{};
    c.in[0] = padP; c.in[1] = padC; c.in[2] = padV;
    c.wr[0] = wrsa; c.wr[1] = wrsb; c.wr[2] = wrsc;
    c.out[0] = fp2; c.out[1] = fc2; c.out[2] = fv2;
    c.bn = bnb + 3 * 1024;
    conv3x3_k<512><<<dim3(32, 4, 6), 256, 0, stream>>>(c);
  }

  // ---- final 1x1 convs -> d_out (fusion_out, p_out, c_out) ----
  final_out_k<<<dim3(32, 3), 256, 0, stream>>>(fp2, fc2, fv2, sm + SO_OW, sm + SO_OB,
                                               sm + SO_PW3, sm + SO_PB3, sm + SO_CW3, sm + SO_CB3,
                                               d_out, flag);
}